// Round 11
// baseline (375.312 us; speedup 1.0000x reference)
//
#include <hip/hip_runtime.h>
#include <hip/hip_bf16.h>

typedef __attribute__((ext_vector_type(8))) short short8;
typedef __attribute__((ext_vector_type(4))) float f32x4;
typedef __attribute__((ext_vector_type(4))) float float4v;
typedef __attribute__((ext_vector_type(4))) unsigned short ushort4v;

// RNE float -> bf16 payload
__device__ __forceinline__ unsigned short f2bf(float f) {
    union { float f; unsigned u; } x; x.f = f;
    unsigned r = x.u + 0x7FFFu + ((x.u >> 16) & 1u);
    return (unsigned short)(r >> 16);
}

// C[k][n] = s(k) * cos(pi * k * (2n+1) / (2N)), N = 512, ortho norm.
__global__ __launch_bounds__(256) void make_dct_mat(unsigned short* __restrict__ Cm) {
    int idx = blockIdx.x * 256 + threadIdx.x;     // 0 .. 512*512-1
    int k = idx >> 9;
    int n = idx & 511;
    int m = (k * (2 * n + 1)) & 2047;             // mod 4N (N=512)
    float ang = (3.14159265358979323846f / 1024.0f) * (float)m;
    float s = (k == 0) ? 0.04419417382415922f : 0.0625f;  // 1/sqrt(512), sqrt(2/512)
    Cm[idx] = f2bf(s * cosf(ang));
}

#define GLD16(g, l) __builtin_amdgcn_global_load_lds( \
    (const __attribute__((address_space(1))) void*)(g), \
    (__attribute__((address_space(3))) void*)(l), 16, 0, 0)

// D[img] = A * B[img]^T  (512x512 row-major per image).
// Block: BM=512 (all output rows) x BN=64 strip; 256 threads = 4 waves,
// wave tile 128x64 -> 32 MFMA per K-step per wave.
//   - B panel (64 rows x 512 K) staged into 64 KB LDS ONCE (one barrier),
//     proven zero-conflict XOR-slot layout (identical bytes to R10).
//   - A (DCT matrix, 512 KB, L2-hot) streamed per K-step into REGISTERS with
//     EXPLICIT double-buffering: loads for kt+1 are issued before the MFMA
//     cluster of kt (hand-pipelined; all indices compile-time).
//   - No barriers, no setprio in the K-loop. 2 blocks/CU.
template <bool B_IS_F32, bool OUT_F32>
__device__ __forceinline__ void dct_gemm_body(
    const unsigned short* __restrict__ A,
    const void* __restrict__ Ball,
    void* __restrict__ Dall)
{
    __shared__ unsigned short Bs[16][64 * 32];   // 64 KB

    // XCD-bijective swizzle (2048 % 8 == 0); an image's 8 strips share an XCD.
    int wg  = blockIdx.x;
    int cpx = gridDim.x >> 3;
    int swz = (wg & 7) * cpx + (wg >> 3);
    int img = swz >> 3;
    int C0  = (swz & 7) * 64;     // output-column strip

    int t    = threadIdx.x;       // 0..255
    int lane = t & 63;
    int wid  = t >> 6;            // 0..3 -> output rows [wid*128, +128)

    const size_t imgoff = (size_t)img * (512 * 512);

    // ---- stage the whole B panel once (layout identical to R10 = verified) ----
    if constexpr (B_IS_F32) {
        const float* Bp = (const float*)Ball + imgoff;
        #pragma unroll
        for (int p = 0; p < 32; ++p) {
            int g    = p * 256 + t;          // 8B granule id, 0..8191
            int kt   = g >> 9;
            int gg   = g & 511;
            int row  = gg >> 3;
            int sL   = (gg >> 1) & 3;
            int half = gg & 1;
            int sG   = sL ^ ((row >> 1) & 3);
            float4v v = *(const float4v*)(Bp + (size_t)(C0 + row) * 512
                                          + kt * 32 + sG * 8 + half * 4);
            ushort4v pk;
            pk.x = f2bf(v.x); pk.y = f2bf(v.y); pk.z = f2bf(v.z); pk.w = f2bf(v.w);
            *(ushort4v*)((unsigned short*)Bs + (size_t)g * 4) = pk;
        }
    } else {
        const unsigned short* Bp = (const unsigned short*)Ball + imgoff;
        const unsigned short* gB = Bp + (size_t)(C0 + (t >> 2)) * 512
                                 + ((t & 3) ^ ((t >> 3) & 3)) * 8;
        #pragma unroll
        for (int p = 0; p < 16; ++p)
            GLD16(gB + p * 32, (unsigned short*)Bs + (size_t)(p * 256 + t) * 8);
    }
    __syncthreads();   // the ONLY barrier

    // ---- hand-pipelined K loop ----
    const unsigned short* gA = A + (size_t)(wid * 128 + (lane & 15)) * 512 + (lane >> 4) * 8;
    const int roff = ((lane >> 4) ^ ((lane >> 1) & 3)) * 8;   // proven read swizzle

    f32x4 acc[8][4] = {};      // 128 VGPR
    short8 av[2][8], bv[2][4]; // explicit double buffers (64 + 32 VGPR)

    #pragma unroll
    for (int m = 0; m < 8; ++m)
        av[0][m] = *(const short8*)(gA + (size_t)m * 16 * 512);
    #pragma unroll
    for (int n = 0; n < 4; ++n)
        bv[0][n] = *(const short8*)(&Bs[0][(n * 16 + (lane & 15)) * 32 + roff]);

    #pragma unroll
    for (int kt = 0; kt < 16; ++kt) {
        const int cur = kt & 1, nxt = cur ^ 1;
        if (kt < 15) {   // issue next-iteration loads BEFORE this iteration's MFMAs
            #pragma unroll
            for (int m = 0; m < 8; ++m)
                av[nxt][m] = *(const short8*)(gA + (size_t)m * 16 * 512 + (kt + 1) * 32);
            #pragma unroll
            for (int n = 0; n < 4; ++n)
                bv[nxt][n] = *(const short8*)(&Bs[kt + 1][(n * 16 + (lane & 15)) * 32 + roff]);
        }
        #pragma unroll
        for (int m = 0; m < 8; ++m)
            #pragma unroll
            for (int n = 0; n < 4; ++n)
                acc[m][n] = __builtin_amdgcn_mfma_f32_16x16x32_bf16(
                                av[cur][m], bv[cur][n], acc[m][n], 0, 0, 0);
    }

    // ---- epilogue: C/D layout col = lane&15, row = (lane>>4)*4 + reg ----
    int r0 = wid * 128 + (lane >> 4) * 4;
    int c0 = C0 + (lane & 15);
    if constexpr (OUT_F32) {
        float* D = (float*)Dall + imgoff;
        #pragma unroll
        for (int m = 0; m < 8; ++m)
            #pragma unroll
            for (int n = 0; n < 4; ++n)
                #pragma unroll
                for (int r = 0; r < 4; ++r)
                    D[(size_t)(r0 + m * 16 + r) * 512 + c0 + n * 16] = acc[m][n][r];
    } else {
        unsigned short* D = (unsigned short*)Dall + imgoff;
        #pragma unroll
        for (int m = 0; m < 8; ++m)
            #pragma unroll
            for (int n = 0; n < 4; ++n)
                #pragma unroll
                for (int r = 0; r < 4; ++r)
                    D[(size_t)(r0 + m * 16 + r) * 512 + c0 + n * 16] = f2bf(acc[m][n][r]);
    }
}

__global__ __launch_bounds__(256, 2) void dct_gemm_s1(
    const unsigned short* __restrict__ A, const float* __restrict__ B,
    unsigned short* __restrict__ D) {
    dct_gemm_body<true, false>(A, B, D);
}

__global__ __launch_bounds__(256, 2) void dct_gemm_s2(
    const unsigned short* __restrict__ A, const unsigned short* __restrict__ B,
    float* __restrict__ D) {
    dct_gemm_body<false, true>(A, B, D);
}

extern "C" void kernel_launch(void* const* d_in, const int* in_sizes, int n_in,
                              void* d_out, int out_size, void* d_ws, size_t ws_size,
                              hipStream_t stream) {
    const float* x = (const float*)d_in[0];
    float* out = (float*)d_out;

    // ws layout: [0, 512KB) = C matrix bf16; [1MB, 1MB+128MB) = intermediate T' bf16
    unsigned short* Cm = (unsigned short*)d_ws;
    unsigned short* Tm = (unsigned short*)((char*)d_ws + (1 << 20));

    int nimg = in_sizes[0] / (512 * 512);   // 256

    make_dct_mat<<<dim3(1024), dim3(256), 0, stream>>>(Cm);
    // Stage 1: T'[b] = C * X[b]^T   (B = fp32 -> cvt in regs -> bf16 LDS, out = bf16)
    dct_gemm_s1<<<dim3(nimg * 8), dim3(256), 0, stream>>>(Cm, x, Tm);
    // Stage 2: Y[b] = C * T'[b]^T = C X C^T  (B = bf16 via global_load_lds, out = fp32)
    dct_gemm_s2<<<dim3(nimg * 8), dim3(256), 0, stream>>>(Cm, Tm, out);
}

// Round 12
// 255.999 us; speedup vs baseline: 1.4661x; 1.4661x over previous
//
#include <hip/hip_runtime.h>
#include <hip/hip_bf16.h>

typedef __attribute__((ext_vector_type(8))) short short8;
typedef __attribute__((ext_vector_type(4))) float f32x4;
typedef __attribute__((ext_vector_type(4))) float float4v;
typedef __attribute__((ext_vector_type(8))) unsigned short ushort8;

// RNE float -> bf16 payload
__device__ __forceinline__ unsigned short f2bf(float f) {
    union { float f; unsigned u; } x; x.f = f;
    unsigned r = x.u + 0x7FFFu + ((x.u >> 16) & 1u);
    return (unsigned short)(r >> 16);
}

// C[k][n] = s(k) * cos(pi * k * (2n+1) / (2N)), N = 512, ortho norm.
__global__ __launch_bounds__(256) void make_dct_mat(unsigned short* __restrict__ Cm) {
    int idx = blockIdx.x * 256 + threadIdx.x;
    int k = idx >> 9;
    int n = idx & 511;
    int m = (k * (2 * n + 1)) & 2047;             // mod 4N
    float ang = (3.14159265358979323846f / 1024.0f) * (float)m;
    float s = (k == 0) ? 0.04419417382415922f : 0.0625f;
    Cm[idx] = f2bf(s * cosf(ang));
}

#define GLD16(g, l) __builtin_amdgcn_global_load_lds( \
    (const __attribute__((address_space(1))) void*)(g), \
    (__attribute__((address_space(3))) void*)(l), 16, 0, 0)
#define BAR()    asm volatile("s_barrier" ::: "memory")
#define VMCNT(n) asm volatile("s_waitcnt vmcnt(" #n ")" ::: "memory")
#define LGKM0()  asm volatile("s_waitcnt lgkmcnt(0)" ::: "memory")

// D[img] = A * B[img]^T, A = DCT matrix (L2-hot), per-image 512x512.
// 8-phase template port: BM=BN=256, BK=64, 8 waves (2Mx4N), wave tile 128x64.
// 8 K-tiles x 4 phases; per phase: {ds_read quadrant frags; stage 1 half;
// counted vmcnt; s_barrier; lgkmcnt(0); setprio+16 MFMA; s_barrier}.
// Halves defined by consumption: A-h0 = rows each wave's m0-3 frags read,
// A-h1 = m4-7; B-h0 = n0-1, B-h1 = n2-3. Quadrant order Q00,Q01,Q11,Q10.
// Sub-tile LDS layout = proven zero-conflict XOR (slotL = slotG ^ ((row>>1)&3)).
template <bool B_IS_F32, bool OUT_F32>
__device__ __forceinline__ void dct_gemm_body(
    const unsigned short* __restrict__ A,
    const void* __restrict__ Ball,
    void* __restrict__ Dall)
{
    // [dbuf][half][ksub][128 rows x 32 K] bf16 = 8 KB subtiles; 64 KB each op.
    __shared__ unsigned short As[2][2][2][4096];
    __shared__ unsigned short Bs[2][2][2][4096];

    // XCD-bijective swizzle (1024 % 8 == 0); an image's 4 tiles stay adjacent
    // on one XCD so the twin R-block's B-panel re-read is an L2 hit.
    int wg  = blockIdx.x;
    int cpx = gridDim.x >> 3;
    int swz = (wg & 7) * cpx + (wg >> 3);
    int img = swz >> 2;
    int R0  = ((swz >> 1) & 1) * 256;   // C-row tile (output rows)
    int C0  = (swz & 1) * 256;          // B-row tile (output cols)

    int t    = threadIdx.x;             // 0..511
    int lane = t & 63;
    int wid  = t >> 6;                  // 0..7
    int wm   = wid >> 2;                // 0..1 -> rows [wm*128,+128)
    int wn   = wid & 3;                 // 0..3 -> cols [wn*64,+64)
    int l15  = lane & 15;
    const int roff = ((lane >> 4) ^ ((lane >> 1) & 3)) * 8;   // proven read swizzle

    const size_t imgoff = (size_t)img * (512 * 512);

    // ---- staging addresses ----
    // A half h: rho = wm_g*64 + j  <->  global row R0 + wm_g*128 + h*64 + j.
    // thread t -> (rho = t>>2, slotL = t&3); source slot pre-XORed.
    const int sXor = ((t & 3) ^ ((t >> 3) & 3)) * 8;
    const unsigned short* gA = A
        + (size_t)(R0 + (t >> 8) * 128 + ((t >> 2) & 63)) * 512 + sXor;
    // B half h: rho = wn_g*32 + j  <->  global row C0 + wn_g*64 + h*32 + j.
    const int bRow = C0 + ((t >> 7) & 3) * 64 + ((t >> 2) & 31);
    const unsigned short* gB16 = nullptr;
    const float* gBf = nullptr;
    if constexpr (B_IS_F32)
        gBf = (const float*)Ball + imgoff + (size_t)bRow * 512 + sXor;
    else
        gB16 = (const unsigned short*)Ball + imgoff + (size_t)bRow * 512 + sXor;

    auto stageA = [&](int d, int kt, int h) {   // 2 GLD16
        GLD16(gA + (size_t)h * 64 * 512 + kt * 64,      &As[d][h][0][t * 8]);
        GLD16(gA + (size_t)h * 64 * 512 + kt * 64 + 32, &As[d][h][1][t * 8]);
    };
    auto stageB = [&](int d, int kt, int h) {   // 2 GLD16 (s2)
        GLD16(gB16 + (size_t)h * 32 * 512 + kt * 64,      &Bs[d][h][0][t * 8]);
        GLD16(gB16 + (size_t)h * 32 * 512 + kt * 64 + 32, &Bs[d][h][1][t * 8]);
    };
    // s1: B half = 4 float4 -> regs (issue early), cvt + 2 ds_write (late).
    float4v rbA[4], rbB[4];
    auto loadB = [&](float4v* rb, int kt, int h) {
        const float* p = gBf + (size_t)h * 32 * 512 + kt * 64;
        rb[0] = *(const float4v*)(p);      rb[1] = *(const float4v*)(p + 4);
        rb[2] = *(const float4v*)(p + 32); rb[3] = *(const float4v*)(p + 36);
    };
    auto writeB = [&](int d, int h, const float4v* rb) {
        #pragma unroll
        for (int ks = 0; ks < 2; ++ks) {
            union { ushort8 u8; __hip_bfloat162 h2[4]; } u;
            u.h2[0] = __float22bfloat162_rn(float2{rb[2*ks].x,   rb[2*ks].y});
            u.h2[1] = __float22bfloat162_rn(float2{rb[2*ks].z,   rb[2*ks].w});
            u.h2[2] = __float22bfloat162_rn(float2{rb[2*ks+1].x, rb[2*ks+1].y});
            u.h2[3] = __float22bfloat162_rn(float2{rb[2*ks+1].z, rb[2*ks+1].w});
            *(ushort8*)(&Bs[d][h][ks][t * 8]) = u.u8;
        }
    };

    short8 avA[4][2], avB[4][2], bvA[2][2], bvB[2][2];
    auto readA = [&](short8 av[4][2], int d, int mh) {    // 8 ds_read_b128
        #pragma unroll
        for (int mq = 0; mq < 4; ++mq)
            #pragma unroll
            for (int ks = 0; ks < 2; ++ks)
                av[mq][ks] = *(const short8*)(
                    &As[d][mh][ks][(wm * 64 + mq * 16 + l15) * 32 + roff]);
    };
    auto readB = [&](short8 bv[2][2], int d, int nh) {    // 4 ds_read_b128
        #pragma unroll
        for (int nq = 0; nq < 2; ++nq)
            #pragma unroll
            for (int ks = 0; ks < 2; ++ks)
                bv[nq][ks] = *(const short8*)(
                    &Bs[d][nh][ks][(wn * 32 + nq * 16 + l15) * 32 + roff]);
    };

    f32x4 acc[8][4] = {};
    auto mfmaQ = [&](short8 av[4][2], short8 bv[2][2], int mh, int nh) {
        __builtin_amdgcn_s_setprio(1);
        #pragma unroll
        for (int mq = 0; mq < 4; ++mq)
            #pragma unroll
            for (int nq = 0; nq < 2; ++nq)
                #pragma unroll
                for (int ks = 0; ks < 2; ++ks)
                    acc[mh*4+mq][nh*2+nq] = __builtin_amdgcn_mfma_f32_16x16x32_bf16(
                        av[mq][ks], bv[nq][ks], acc[mh*4+mq][nh*2+nq], 0, 0, 0);
        __builtin_amdgcn_s_setprio(0);
    };

    // ---- prologue: fill buf0; leave [B0h1?,A0h1] in flight per ledger ----
    if constexpr (B_IS_F32) {
        stageA(0, 0, 0);        // q: [A0h0(2)]
        loadB(rbA, 0, 0);       //    +rbA(4)
        loadB(rbB, 0, 1);       //    +rbB(4)
        stageA(0, 0, 1);        //    +A0h1(2) = 12
        VMCNT(6);               // retire A0h0+rbA; keep [rbB,A0h1]
        writeB(0, 0, rbA);
        VMCNT(2);               // retire rbB; keep [A0h1]
        writeB(0, 1, rbB);
        LGKM0();
        BAR();
    } else {
        stageA(0, 0, 0); stageB(0, 0, 0); stageB(0, 0, 1); stageA(0, 0, 1);
        VMCNT(4);               // retire A0h0,B0h0; keep [B0h1,A0h1]
        BAR();
    }

    // ---- 8 K-tiles x 4 phases, counted vmcnt ledger in comments ----
    #pragma unroll
    for (int kt = 0; kt < 8; ++kt) {
        const int d = kt & 1, e = d ^ 1;
        // P0: Q(m0-3, n0-1)
        readA(avA, d, 0); readB(bvA, d, 0);               // 12 ds_read
        if constexpr (B_IS_F32) {
            if (kt < 7) loadB(rbA, kt + 1, 0);            // no wait needed
        } else {
            if (kt < 7) { stageA(e, kt + 1, 0); VMCNT(4); }  // retire B(kt)h1
            else        { VMCNT(2); }                        // tail
        }
        BAR(); LGKM0();
        mfmaQ(avA, bvA, 0, 0);
        BAR();
        // P1: Q(m0-3, n2-3)
        readB(bvB, d, 1);                                  // 4 ds_read
        if constexpr (B_IS_F32) {
            if (kt < 7) { loadB(rbB, kt + 1, 1); VMCNT(8); } // retire A(kt)h1
            else        { VMCNT(0); }
        } else {
            if (kt < 7) { stageB(e, kt + 1, 0); VMCNT(4); }  // retire A(kt)h1
            else        { VMCNT(0); }
        }
        BAR(); LGKM0();
        mfmaQ(avA, bvB, 0, 1);
        BAR();
        // P2: Q(m4-7, n2-3)
        readA(avB, d, 1);                                  // 8 ds_read
        if constexpr (B_IS_F32) {
            if (kt < 7) { VMCNT(4);                        // retire rbA (keep rbB)
                          writeB(e, 0, rbA);
                          stageA(e, kt + 1, 0); }
        } else {
            if (kt < 7) { stageB(e, kt + 1, 1); VMCNT(4); }
        }
        BAR(); LGKM0();
        mfmaQ(avB, bvB, 1, 1);
        BAR();
        // P3: Q(m4-7, n0-1)  (reuses avB + bvA; 0 ds_read)
        if constexpr (B_IS_F32) {
            if (kt < 7) { VMCNT(2);                        // retire rbB (keep A'h0)
                          writeB(e, 1, rbB);
                          stageA(e, kt + 1, 1);
                          VMCNT(2); }                      // retire A'h0 (keep A'h1)
        } else {
            if (kt < 7) { stageA(e, kt + 1, 1); VMCNT(4); } // retire A'h0,B'h0
        }
        BAR(); LGKM0();
        mfmaQ(avB, bvA, 1, 0);
        BAR();
    }

    // ---- epilogue: C/D layout col = lane&15, row = (lane>>4)*4 + reg ----
    int r0 = R0 + wm * 128 + (lane >> 4) * 4;
    int c0 = C0 + wn * 64 + l15;
    if constexpr (OUT_F32) {
        float* D = (float*)Dall + imgoff;
        #pragma unroll
        for (int m = 0; m < 8; ++m)
            #pragma unroll
            for (int n = 0; n < 4; ++n)
                #pragma unroll
                for (int r = 0; r < 4; ++r)
                    D[(size_t)(r0 + (m >> 2) * 64 + (m & 3) * 16 + r) * 512
                      + c0 + (n >> 1) * 32 + (n & 1) * 16] = acc[m][n][r];
    } else {
        unsigned short* D = (unsigned short*)Dall + imgoff;
        #pragma unroll
        for (int m = 0; m < 8; ++m)
            #pragma unroll
            for (int n = 0; n < 4; ++n)
                #pragma unroll
                for (int r = 0; r < 4; ++r)
                    D[(size_t)(r0 + (m >> 2) * 64 + (m & 3) * 16 + r) * 512
                      + c0 + (n >> 1) * 32 + (n & 1) * 16] = f2bf(acc[m][n][r]);
    }
}

__global__ __launch_bounds__(512, 2) void dct_gemm_s1(
    const unsigned short* __restrict__ A, const float* __restrict__ B,
    unsigned short* __restrict__ D) {
    dct_gemm_body<true, false>(A, B, D);
}

__global__ __launch_bounds__(512, 2) void dct_gemm_s2(
    const unsigned short* __restrict__ A, const unsigned short* __restrict__ B,
    float* __restrict__ D) {
    dct_gemm_body<false, true>(A, B, D);
}

extern "C" void kernel_launch(void* const* d_in, const int* in_sizes, int n_in,
                              void* d_out, int out_size, void* d_ws, size_t ws_size,
                              hipStream_t stream) {
    const float* x = (const float*)d_in[0];
    float* out = (float*)d_out;

    // ws layout: [0, 512KB) = C matrix bf16; [1MB, 1MB+128MB) = intermediate V bf16
    unsigned short* Cm = (unsigned short*)d_ws;
    unsigned short* Tm = (unsigned short*)((char*)d_ws + (1 << 20));

    int nimg = in_sizes[0] / (512 * 512);   // 256

    make_dct_mat<<<dim3(1024), dim3(256), 0, stream>>>(Cm);
    // Stage 1: V[b] = C * X[b]^T   (B = fp32 -> cvt in regs -> bf16 LDS, out = bf16)
    dct_gemm_s1<<<dim3(nimg * 4), dim3(512), 0, stream>>>(Cm, x, Tm);
    // Stage 2: Y[b] = C * V[b]^T = C X C^T  (B = bf16 via global_load_lds, out = fp32)
    dct_gemm_s2<<<dim3(nimg * 4), dim3(512), 0, stream>>>(Cm, Tm, out);
}

// Round 13
// 250.129 us; speedup vs baseline: 1.5005x; 1.0235x over previous
//
#include <hip/hip_runtime.h>
#include <hip/hip_bf16.h>

typedef __attribute__((ext_vector_type(8))) short short8;
typedef __attribute__((ext_vector_type(4))) float f32x4;
typedef __attribute__((ext_vector_type(4))) float float4v;
typedef __attribute__((ext_vector_type(8))) unsigned short ushort8;

// RNE float -> bf16 payload
__device__ __forceinline__ unsigned short f2bf(float f) {
    union { float f; unsigned u; } x; x.f = f;
    unsigned r = x.u + 0x7FFFu + ((x.u >> 16) & 1u);
    return (unsigned short)(r >> 16);
}

// C[k][n] = s(k) * cos(pi * k * (2n+1) / (2N)), N = 512, ortho norm.
__global__ __launch_bounds__(256) void make_dct_mat(unsigned short* __restrict__ Cm) {
    int idx = blockIdx.x * 256 + threadIdx.x;
    int k = idx >> 9;
    int n = idx & 511;
    int m = (k * (2 * n + 1)) & 2047;             // mod 4N
    float ang = (3.14159265358979323846f / 1024.0f) * (float)m;
    float s = (k == 0) ? 0.04419417382415922f : 0.0625f;
    Cm[idx] = f2bf(s * cosf(ang));
}

#define GLD16(g, l) __builtin_amdgcn_global_load_lds( \
    (const __attribute__((address_space(1))) void*)(g), \
    (__attribute__((address_space(3))) void*)(l), 16, 0, 0)
#define BAR()    asm volatile("s_barrier" ::: "memory")
#define VMCNT(n) asm volatile("s_waitcnt vmcnt(" #n ")" ::: "memory")
#define LGKM0()  asm volatile("s_waitcnt lgkmcnt(0)" ::: "memory")
#define MEMORD() asm volatile("" ::: "memory")   // pin VMEM issue order (FIFO ledger)

// D[img] = A * B[img]^T, A = DCT matrix (L2-hot), per-image 512x512.
// 8-phase template port: BM=BN=256, BK=64, 8 waves (2Mx4N), wave tile 128x64.
// 8 K-tiles x 4 phases; per phase: {ds_read quadrant frags; stage/issue;
// counted vmcnt (4, never 0 mid-loop); s_barrier; lgkmcnt(0); MFMA; s_barrier}.
// s1 (fp32 B): quarter-chunk reg staging (2 float4 = 8 VGPR per chunk, two
// alternating buffers cU/cV, load at phase p -> cvt+ds_write at phase p+1)
// -> ledger peak 16 VGPR (was 32) to kill the R12 spill.
// Sub-tile LDS layout = proven zero-conflict XOR (slotL = slotG ^ ((row>>1)&3)).
template <bool B_IS_F32, bool OUT_F32>
__device__ __forceinline__ void dct_gemm_body(
    const unsigned short* __restrict__ A,
    const void* __restrict__ Ball,
    void* __restrict__ Dall)
{
    // [dbuf][half][ksub][128 rows x 32 K] bf16 = 8 KB subtiles; 64 KB each op.
    __shared__ unsigned short As[2][2][2][4096];
    __shared__ unsigned short Bs[2][2][2][4096];

    // XCD-bijective swizzle (1024 % 8 == 0); an image's 4 tiles stay adjacent
    // on one XCD so the twin R-block's B-panel re-read is an L2 hit.
    int wg  = blockIdx.x;
    int cpx = gridDim.x >> 3;
    int swz = (wg & 7) * cpx + (wg >> 3);
    int img = swz >> 2;
    int R0  = ((swz >> 1) & 1) * 256;   // C-row tile (output rows)
    int C0  = (swz & 1) * 256;          // B-row tile (output cols)

    int t    = threadIdx.x;             // 0..511
    int lane = t & 63;
    int wid  = t >> 6;                  // 0..7
    int wm   = wid >> 2;                // 0..1 -> rows [wm*128,+128)
    int wn   = wid & 3;                 // 0..3 -> cols [wn*64,+64)
    int l15  = lane & 15;
    const int roff = ((lane >> 4) ^ ((lane >> 1) & 3)) * 8;   // proven read swizzle

    const size_t imgoff = (size_t)img * (512 * 512);

    // ---- staging addresses (pre-swizzled 16B slot) ----
    const int sXor = ((t & 3) ^ ((t >> 3) & 3)) * 8;
    const unsigned short* gA = A
        + (size_t)(R0 + (t >> 8) * 128 + ((t >> 2) & 63)) * 512 + sXor;
    const int bRow = C0 + ((t >> 7) & 3) * 64 + ((t >> 2) & 31);
    const unsigned short* gB16 = nullptr;
    const float* gBf = nullptr;
    if constexpr (B_IS_F32)
        gBf = (const float*)Ball + imgoff + (size_t)bRow * 512 + sXor;
    else
        gB16 = (const unsigned short*)Ball + imgoff + (size_t)bRow * 512 + sXor;

    auto stageA = [&](int d, int kt, int h) {   // 2 GLD16
        GLD16(gA + (size_t)h * 64 * 512 + kt * 64,      &As[d][h][0][t * 8]);
        GLD16(gA + (size_t)h * 64 * 512 + kt * 64 + 32, &As[d][h][1][t * 8]);
    };
    auto stageB = [&](int d, int kt, int h) {   // 2 GLD16 (s2)
        GLD16(gB16 + (size_t)h * 32 * 512 + kt * 64,      &Bs[d][h][0][t * 8]);
        GLD16(gB16 + (size_t)h * 32 * 512 + kt * 64 + 32, &Bs[d][h][1][t * 8]);
    };

    // s1 quarter-chunk staging: chunk (h,ks) = 2 float4 / thread.
    float4v cU[2], cV[2];
    auto loadChunk = [&](float4v* cb, int kt, int h, int ks) {   // 2 vmem loads
        const float* p = gBf + (size_t)h * 32 * 512 + kt * 64 + ks * 32;
        cb[0] = *(const float4v*)(p);
        cb[1] = *(const float4v*)(p + 4);
    };
    auto writeChunk = [&](int dbuf, int h, int ks, const float4v* cb) { // 1 ds_write_b128
        union { ushort8 u8; __hip_bfloat162 h2[4]; } u;
        u.h2[0] = __float22bfloat162_rn(float2{cb[0].x, cb[0].y});
        u.h2[1] = __float22bfloat162_rn(float2{cb[0].z, cb[0].w});
        u.h2[2] = __float22bfloat162_rn(float2{cb[1].x, cb[1].y});
        u.h2[3] = __float22bfloat162_rn(float2{cb[1].z, cb[1].w});
        *(ushort8*)(&Bs[dbuf][h][ks][t * 8]) = u.u8;
    };

    short8 avA[4][2], avB[4][2], bvA[2][2], bvB[2][2];
    auto readA = [&](short8 av[4][2], int d, int mh) {    // 8 ds_read_b128
        #pragma unroll
        for (int mq = 0; mq < 4; ++mq)
            #pragma unroll
            for (int ks = 0; ks < 2; ++ks)
                av[mq][ks] = *(const short8*)(
                    &As[d][mh][ks][(wm * 64 + mq * 16 + l15) * 32 + roff]);
    };
    auto readB = [&](short8 bv[2][2], int d, int nh) {    // 4 ds_read_b128
        #pragma unroll
        for (int nq = 0; nq < 2; ++nq)
            #pragma unroll
            for (int ks = 0; ks < 2; ++ks)
                bv[nq][ks] = *(const short8*)(
                    &Bs[d][nh][ks][(wn * 32 + nq * 16 + l15) * 32 + roff]);
    };

    f32x4 acc[8][4] = {};
    auto mfmaQ = [&](short8 av[4][2], short8 bv[2][2], int mh, int nh) {
        __builtin_amdgcn_s_setprio(1);
        #pragma unroll
        for (int mq = 0; mq < 4; ++mq)
            #pragma unroll
            for (int nq = 0; nq < 2; ++nq)
                #pragma unroll
                for (int ks = 0; ks < 2; ++ks)
                    acc[mh*4+mq][nh*2+nq] = __builtin_amdgcn_mfma_f32_16x16x32_bf16(
                        av[mq][ks], bv[nq][ks], acc[mh*4+mq][nh*2+nq], 0, 0, 0);
        __builtin_amdgcn_s_setprio(0);
    };

    // ---- prologue: fill buf0, leaving FIFO = [Ah1(0), c3-or-B0h1] (4 ops) ----
    if constexpr (B_IS_F32) {
        loadChunk(cU, 0, 0, 0);   MEMORD();   // c0(0) [2]
        stageA(0, 0, 0);          MEMORD();   // Ah0(0) [2]
        loadChunk(cV, 0, 0, 1);               // c1(0) [2]  queue=6
        VMCNT(4);                             // retire c0
        writeChunk(0, 0, 0, cU);
        loadChunk(cU, 0, 1, 0);   MEMORD();   // c2(0) [2]
        stageA(0, 0, 1);                      // Ah1(0) [2]  queue=8
        VMCNT(4);                             // retire Ah0, c1
        writeChunk(0, 0, 1, cV);
        loadChunk(cV, 0, 1, 1);               // c3(0) [2]  queue=6
        VMCNT(4);                             // retire c2; FIFO=[Ah1,c3]
        writeChunk(0, 1, 0, cU);
        LGKM0();
        BAR();
    } else {
        stageA(0, 0, 0); MEMORD(); stageB(0, 0, 0); MEMORD();
        stageB(0, 0, 1); MEMORD(); stageA(0, 0, 1);
        VMCNT(4);               // retire A0h0,B0h0; keep [B0h1,A0h1]
        BAR();
    }

    // ---- 8 K-tiles x 4 phases; steady-state FIFO ledger in comments ----
    #pragma unroll
    for (int kt = 0; kt < 8; ++kt) {
        const int d = kt & 1, e = d ^ 1;
        // P0  entry FIFO (s1): [Ah1(kt), c3(kt)]
        readA(avA, d, 0); readB(bvA, d, 0);               // 12 ds_read
        if constexpr (B_IS_F32) {
            if (kt < 7) { loadChunk(cU, kt + 1, 0, 0); MEMORD();
                          stageA(e, kt + 1, 0);               // queue=8
                          VMCNT(4); }                         // retire Ah1(kt),c3(kt)
            else        { VMCNT(0); }
            writeChunk(d, 1, 1, cV);                          // c3(kt) -> current buf
        } else {
            if (kt < 7) { stageA(e, kt + 1, 0); VMCNT(4); }   // retire B(kt)h1
            else        { VMCNT(2); }
        }
        BAR(); LGKM0();
        mfmaQ(avA, bvA, 0, 0);
        BAR();
        // P1  FIFO (s1): [c0', Ah0']
        readB(bvB, d, 1);                                  // 4 ds_read
        if constexpr (B_IS_F32) {
            if (kt < 7) { loadChunk(cV, kt + 1, 0, 1);         // queue=6
                          VMCNT(4);                            // retire c0'
                          writeChunk(e, 0, 0, cU); }
        } else {
            if (kt < 7) { stageB(e, kt + 1, 0); VMCNT(4); }    // retire A(kt)h1
            else        { VMCNT(0); }
        }
        BAR(); LGKM0();
        mfmaQ(avA, bvB, 0, 1);
        BAR();
        // P2  FIFO (s1): [Ah0', c1']
        readA(avB, d, 1);                                  // 8 ds_read
        if constexpr (B_IS_F32) {
            if (kt < 7) { loadChunk(cU, kt + 1, 1, 0); MEMORD();
                          stageA(e, kt + 1, 1);                // queue=8
                          VMCNT(4);                            // retire Ah0',c1'
                          writeChunk(e, 0, 1, cV); }
        } else {
            if (kt < 7) { stageB(e, kt + 1, 1); VMCNT(4); }
        }
        BAR(); LGKM0();
        mfmaQ(avB, bvB, 1, 1);
        BAR();
        // P3  FIFO (s1): [c2', Ah1']
        if constexpr (B_IS_F32) {
            if (kt < 7) { loadChunk(cV, kt + 1, 1, 1);         // queue=6
                          VMCNT(4);                            // retire c2'
                          writeChunk(e, 1, 0, cU); }           // FIFO=[Ah1',c3']
        } else {
            if (kt < 7) { stageA(e, kt + 1, 1); VMCNT(4); }    // retire A'h0,B'h0
        }
        BAR(); LGKM0();
        mfmaQ(avB, bvA, 1, 0);
        BAR();
    }

    // ---- epilogue: C/D layout col = lane&15, row = (lane>>4)*4 + reg ----
    int r0 = R0 + wm * 128 + (lane >> 4) * 4;
    int c0 = C0 + wn * 64 + l15;
    if constexpr (OUT_F32) {
        float* D = (float*)Dall + imgoff;
        #pragma unroll
        for (int m = 0; m < 8; ++m)
            #pragma unroll
            for (int n = 0; n < 4; ++n)
                #pragma unroll
                for (int r = 0; r < 4; ++r)
                    D[(size_t)(r0 + (m >> 2) * 64 + (m & 3) * 16 + r) * 512
                      + c0 + (n >> 1) * 32 + (n & 1) * 16] = acc[m][n][r];
    } else {
        unsigned short* D = (unsigned short*)Dall + imgoff;
        #pragma unroll
        for (int m = 0; m < 8; ++m)
            #pragma unroll
            for (int n = 0; n < 4; ++n)
                #pragma unroll
                for (int r = 0; r < 4; ++r)
                    D[(size_t)(r0 + (m >> 2) * 64 + (m & 3) * 16 + r) * 512
                      + c0 + (n >> 1) * 32 + (n & 1) * 16] = f2bf(acc[m][n][r]);
    }
}

__global__ __launch_bounds__(512, 2) void dct_gemm_s1(
    const unsigned short* __restrict__ A, const float* __restrict__ B,
    unsigned short* __restrict__ D) {
    dct_gemm_body<true, false>(A, B, D);
}

__global__ __launch_bounds__(512, 2) void dct_gemm_s2(
    const unsigned short* __restrict__ A, const unsigned short* __restrict__ B,
    float* __restrict__ D) {
    dct_gemm_body<false, true>(A, B, D);
}

extern "C" void kernel_launch(void* const* d_in, const int* in_sizes, int n_in,
                              void* d_out, int out_size, void* d_ws, size_t ws_size,
                              hipStream_t stream) {
    const float* x = (const float*)d_in[0];
    float* out = (float*)d_out;

    // ws layout: [0, 512KB) = C matrix bf16; [1MB, 1MB+128MB) = intermediate V bf16
    unsigned short* Cm = (unsigned short*)d_ws;
    unsigned short* Tm = (unsigned short*)((char*)d_ws + (1 << 20));

    int nimg = in_sizes[0] / (512 * 512);   // 256

    make_dct_mat<<<dim3(1024), dim3(256), 0, stream>>>(Cm);
    // Stage 1: V[b] = C * X[b]^T   (B = fp32 -> quarter-chunk cvt -> bf16 LDS)
    dct_gemm_s1<<<dim3(nimg * 4), dim3(512), 0, stream>>>(Cm, x, Tm);
    // Stage 2: Y[b] = C * V[b]^T = C X C^T  (B = bf16 via global_load_lds)
    dct_gemm_s2<<<dim3(nimg * 4), dim3(512), 0, stream>>>(Cm, Tm, out);
}